// Round 10
// baseline (775.070 us; speedup 1.0000x reference)
//
#include <hip/hip_runtime.h>
#include <hip/hip_fp16.h>

#define HIDDIM 256
#define NHEADS 8
#define SCORE_SHIFT 4.0f
#define WSLOTS 64

struct __attribute__((aligned(8))) half4s { __half2 a, b; };

typedef _Float16 f16x8 __attribute__((ext_vector_type(8)));
typedef float f32x4 __attribute__((ext_vector_type(4)));

// ---------------- converts ----------------
__global__ __launch_bounds__(256) void cvt_f2h(
    const float* __restrict__ in, __half* __restrict__ out, int n) {
  const int i = blockIdx.x * 256 + threadIdx.x;
  if (i < n) out[i] = __float2half(in[i]);
}

// in [K][N] fp32 -> out [N][K] fp16 (transposed)
__global__ __launch_bounds__(256) void cvt_transpose(
    const float* __restrict__ in, __half* __restrict__ out, int K, int N) {
  const int idx = blockIdx.x * 256 + threadIdx.x;
  if (idx >= K * N) return;
  const int n = idx / K, k = idx - n * K;
  out[idx] = __float2half(in[(size_t)k * N + n]);
}

// ---------------- MFMA GEMM: C16[M,N] = act(A16[M,K] @ Wt16[N,K]^T + bias) ----------------
template <int RELU>
__global__ __launch_bounds__(256) void gemm_mfma(
    const _Float16* __restrict__ A, const _Float16* __restrict__ Wt,
    const float* __restrict__ bias, _Float16* __restrict__ C,
    int M, int N, int K) {
  const int wv = threadIdx.x >> 6;
  const int lane = threadIdx.x & 63;
  const int bn = blockIdx.x * 64;
  const int bm = blockIdx.y * 64 + wv * 16;
  const int fr = lane & 15;
  const int kb = lane >> 4;

  int arow = bm + fr; if (arow >= M) arow = M - 1;
  const _Float16* ap = A + (size_t)arow * K + kb * 8;
  const _Float16* bp = Wt + (size_t)(bn + fr) * K + kb * 8;

  f32x4 acc[4] = {};
  for (int k0 = 0; k0 < K; k0 += 32) {
    const f16x8 a = *(const f16x8*)(ap + k0);
    #pragma unroll
    for (int nt = 0; nt < 4; ++nt) {
      const f16x8 b = *(const f16x8*)(bp + (size_t)nt * 16 * K + k0);
      acc[nt] = __builtin_amdgcn_mfma_f32_16x16x32_f16(a, b, acc[nt], 0, 0, 0);
    }
  }
  #pragma unroll
  for (int r = 0; r < 4; ++r) {
    const int row = bm + (lane >> 4) * 4 + r;
    if (row >= M) continue;
    #pragma unroll
    for (int nt = 0; nt < 4; ++nt) {
      const int col = bn + nt * 16 + fr;
      float v = acc[nt][r] + bias[col];
      if (RELU && v < 0.f) v = 0.f;
      C[(size_t)row * N + col] = (_Float16)v;
    }
  }
}

// ---------------- CSR build (by destination; stores SRC and DST per slot) ----------------
__global__ __launch_bounds__(256) void count_deg(
    const int* __restrict__ ei, int* __restrict__ deg, int E, int Nn) {
  const int t = blockIdx.x * blockDim.x + threadIdx.x;
  const int ET = E + Nn;
  if (t >= ET) return;
  const int dst = (t < E) ? ei[E + t] : (t - E);
  atomicAdd(&deg[dst], 1);
}

__global__ __launch_bounds__(1024) void scan_deg(
    const int* __restrict__ deg, int* __restrict__ rowptr, int Nn) {
  __shared__ int wsum[16];
  __shared__ int carry_s;
  const int tid = threadIdx.x;
  const int wid = tid >> 6, lane = tid & 63;
  if (tid == 0) { carry_s = 0; rowptr[0] = 0; }
  __syncthreads();
  for (int base = 0; base < Nn; base += 1024) {
    const int i = base + tid;
    int s = (i < Nn) ? deg[i] : 0;
    #pragma unroll
    for (int off = 1; off < 64; off <<= 1) {
      int t = __shfl_up(s, off);
      if (lane >= off) s += t;
    }
    if (lane == 63) wsum[wid] = s;
    __syncthreads();
    if (wid == 0 && lane < 16) {
      int ws = wsum[lane];
      #pragma unroll
      for (int off = 1; off < 16; off <<= 1) {
        int t = __shfl_up(ws, off);
        if (lane >= off) ws += t;
      }
      wsum[lane] = ws;
    }
    __syncthreads();
    const int prefix = (wid > 0 ? wsum[wid - 1] : 0) + carry_s;
    if (i < Nn) rowptr[i + 1] = s + prefix;
    __syncthreads();
    if (tid == 0) carry_s += wsum[15];
    __syncthreads();
  }
}

__global__ __launch_bounds__(256) void fill_csr(
    const int* __restrict__ ei, const int* __restrict__ rowptr,
    int* __restrict__ cursor, int* __restrict__ csr, int* __restrict__ csrd,
    int E, int Nn) {
  const int t = blockIdx.x * blockDim.x + threadIdx.x;
  const int ET = E + Nn;
  if (t >= ET) return;
  int src, dst;
  if (t < E) { src = ei[t]; dst = ei[E + t]; }
  else { src = t - E; dst = t - E; }
  const int pos = atomicAdd(&cursor[dst], 1);
  csr[rowptr[dst] + pos] = src;
  csrd[rowptr[dst] + pos] = dst;
}

// ---------------- zero boundary-node accumulators ----------------
// candidates: first and last slot's node of every wave-range
__global__ __launch_bounds__(256) void zero_boundary(
    const int* __restrict__ csrd, float* __restrict__ accf,
    float* __restrict__ accd, int ET) {
  const int cand = blockIdx.x;
  const int ch = threadIdx.x;
  const int w = cand >> 1;
  int slot = (cand & 1) ? min(w * WSLOTS + WSLOTS, ET) - 1 : w * WSLOTS;
  if (slot >= ET) slot = ET - 1;
  const int n = csrd[slot];
  accf[(size_t)n * HIDDIM + ch] = 0.f;
  if (ch < NHEADS) accd[n * NHEADS + ch] = 0.f;
}

// ---------------- segmented GATv2 aggregation over CSR slot ranges ----------------
// one wave per WSLOTS consecutive CSR slots; lane owns channels [4*lane, 4*lane+4)
// per slot: gather xl row, score (3-shuffle head reduce), w = exp(s - SHIFT),
// accumulate (sum w*xl, sum w) in registers; flush per node run (plain store if
// run entirely inside this range, else atomicAdd).
__global__ __launch_bounds__(256) void edge_seg(
    const __half* __restrict__ xl, const __half* __restrict__ xr,
    const int* __restrict__ csr, const int* __restrict__ csrd,
    const int* __restrict__ rowptr, const float* __restrict__ att,
    float* __restrict__ accf, float* __restrict__ accd, int ET) {
  const int wgid = (int)((blockIdx.x * (size_t)blockDim.x + threadIdx.x) >> 6);
  const int lane = threadIdx.x & 63;
  const int s0 = wgid * WSLOTS;
  if (s0 >= ET) return;
  const int s1 = min(s0 + WSLOTS, ET);
  const int h = lane >> 3;
  const float4 at4 = *(const float4*)(att + lane * 4);

  int cur = csrd[s0];
  float4 xr4;
  {
    const half4s xh = *((const half4s*)(xr + (size_t)cur * HIDDIM) + lane);
    const float2 f01 = __half22float2(xh.a);
    const float2 f23 = __half22float2(xh.b);
    xr4 = make_float4(f01.x, f01.y, f23.x, f23.y);
  }
  float4 acc = make_float4(0.f, 0.f, 0.f, 0.f);
  float den = 0.f;

  for (int j = s0; j < s1; ++j) {
    const int dst = csrd[j];
    if (dst != cur) {
      const int rp0 = rowptr[cur], rp1 = rowptr[cur + 1];
      float* ap = accf + (size_t)cur * HIDDIM + lane * 4;
      if (rp0 >= s0 && rp1 <= s1) {
        *(float4*)ap = acc;
        if ((lane & 7) == 0) accd[cur * NHEADS + h] = den;
      } else {
        atomicAdd(ap + 0, acc.x);
        atomicAdd(ap + 1, acc.y);
        atomicAdd(ap + 2, acc.z);
        atomicAdd(ap + 3, acc.w);
        if ((lane & 7) == 0) atomicAdd(&accd[cur * NHEADS + h], den);
      }
      acc = make_float4(0.f, 0.f, 0.f, 0.f);
      den = 0.f;
      cur = dst;
      const half4s xh = *((const half4s*)(xr + (size_t)cur * HIDDIM) + lane);
      const float2 f01 = __half22float2(xh.a);
      const float2 f23 = __half22float2(xh.b);
      xr4 = make_float4(f01.x, f01.y, f23.x, f23.y);
    }
    const int src = csr[j];
    const half4s ah = *((const half4s*)(xl + (size_t)src * HIDDIM) + lane);
    const float2 f01 = __half22float2(ah.a);
    const float2 f23 = __half22float2(ah.b);
    const float4 a = make_float4(f01.x, f01.y, f23.x, f23.y);
    float v, s;
    v = a.x + xr4.x; v = v >= 0.f ? v : 0.2f * v; s = v * at4.x;
    v = a.y + xr4.y; v = v >= 0.f ? v : 0.2f * v; s = fmaf(v, at4.y, s);
    v = a.z + xr4.z; v = v >= 0.f ? v : 0.2f * v; s = fmaf(v, at4.z, s);
    v = a.w + xr4.w; v = v >= 0.f ? v : 0.2f * v; s = fmaf(v, at4.w, s);
    s += __shfl_xor(s, 1);
    s += __shfl_xor(s, 2);
    s += __shfl_xor(s, 4);
    const float w = __expf(s - SCORE_SHIFT);
    acc.x = fmaf(w, a.x, acc.x);
    acc.y = fmaf(w, a.y, acc.y);
    acc.z = fmaf(w, a.z, acc.z);
    acc.w = fmaf(w, a.w, acc.w);
    den += w;
  }
  // final flush
  {
    const int rp0 = rowptr[cur], rp1 = rowptr[cur + 1];
    float* ap = accf + (size_t)cur * HIDDIM + lane * 4;
    if (rp0 >= s0 && rp1 <= s1) {
      *(float4*)ap = acc;
      if ((lane & 7) == 0) accd[cur * NHEADS + h] = den;
    } else {
      atomicAdd(ap + 0, acc.x);
      atomicAdd(ap + 1, acc.y);
      atomicAdd(ap + 2, acc.z);
      atomicAdd(ap + 3, acc.w);
      if ((lane & 7) == 0) atomicAdd(&accd[cur * NHEADS + h], den);
    }
  }
}

// ---------------- node epilogue: bias+relu then LN (MODE0, ->fp16) or pool (MODE1) ----------------
template <int MODE>
__global__ __launch_bounds__(256) void node_fin(
    const float* __restrict__ accf, const float* __restrict__ accd,
    const float* __restrict__ bias, const float* __restrict__ lng,
    const float* __restrict__ lnb, const int* __restrict__ batch,
    float* __restrict__ pooled, float* __restrict__ counts,
    __half* __restrict__ outp, int Nn) {
  const int n = (int)((blockIdx.x * (size_t)blockDim.x + threadIdx.x) >> 6);
  const int lane = threadIdx.x & 63;
  if (n >= Nn) return;
  const float4 a4 = *(const float4*)(accf + (size_t)n * HIDDIM + lane * 4);
  const float dh = accd[n * NHEADS + (lane >> 3)];
  const float inv_d = 1.f / dh;
  const float4 bb = *(const float4*)(bias + lane * 4);
  float t0 = fmaf(a4.x, inv_d, bb.x); t0 = t0 > 0.f ? t0 : 0.f;
  float t1 = fmaf(a4.y, inv_d, bb.y); t1 = t1 > 0.f ? t1 : 0.f;
  float t2 = fmaf(a4.z, inv_d, bb.z); t2 = t2 > 0.f ? t2 : 0.f;
  float t3 = fmaf(a4.w, inv_d, bb.w); t3 = t3 > 0.f ? t3 : 0.f;

  if (MODE == 0) {
    float s = t0 + t1 + t2 + t3;
    #pragma unroll
    for (int mm = 1; mm < 64; mm <<= 1) s += __shfl_xor(s, mm);
    const float mu = s * (1.f / HIDDIM);
    const float d0 = t0 - mu, d1 = t1 - mu, d2 = t2 - mu, d3 = t3 - mu;
    float q = d0 * d0 + d1 * d1 + d2 * d2 + d3 * d3;
    #pragma unroll
    for (int mm = 1; mm < 64; mm <<= 1) q += __shfl_xor(q, mm);
    const float inv = rsqrtf(q * (1.f / HIDDIM) + 1e-5f);
    const float4 g4 = *(const float4*)(lng + lane * 4);
    const float4 b4 = *(const float4*)(lnb + lane * 4);
    half4s ho;
    ho.a = __floats2half2_rn(d0 * inv * g4.x + b4.x, d1 * inv * g4.y + b4.y);
    ho.b = __floats2half2_rn(d2 * inv * g4.z + b4.z, d3 * inv * g4.w + b4.w);
    *((half4s*)outp + (size_t)n * (HIDDIM / 4) + lane) = ho;
  } else {
    const int g = batch[n];
    float* p = pooled + (size_t)g * HIDDIM + lane * 4;
    atomicAdd(p + 0, t0);
    atomicAdd(p + 1, t1);
    atomicAdd(p + 2, t2);
    atomicAdd(p + 3, t3);
    if (lane == 0) atomicAdd(&counts[g], 1.f);
  }
}

// ---------------- head MLP ----------------
__global__ __launch_bounds__(256) void head_kernel(
    const float* __restrict__ pooled, const float* __restrict__ counts,
    const float* __restrict__ h1w, const float* __restrict__ h1b,
    const float* __restrict__ h2w, const float* __restrict__ h2b,
    float* __restrict__ out, int G, int H1, int OUT) {
  __shared__ float P[16][HIDDIM];
  __shared__ float Hh[16][128];
  const int tid = threadIdx.x;
  for (int i = tid; i < G * HIDDIM; i += 256) {
    const int g = i / HIDDIM, c = i % HIDDIM;
    float cnt = counts[g];
    if (cnt < 1.f) cnt = 1.f;
    P[g][c] = pooled[i] / cnt;
  }
  __syncthreads();
  for (int i = tid; i < G * H1; i += 256) {
    const int g = i / H1, j = i % H1;
    float s = h1b[j];
    for (int k = 0; k < HIDDIM; ++k) s = fmaf(P[g][k], h1w[k * H1 + j], s);
    Hh[g][j] = s > 0.f ? s : 0.f;
  }
  __syncthreads();
  for (int i = tid; i < G * OUT; i += 256) {
    const int g = i / OUT, o = i % OUT;
    float s = h2b[o];
    for (int k = 0; k < H1; ++k) s = fmaf(Hh[g][k], h2w[k * OUT + o], s);
    out[i] = s;
  }
}

extern "C" void kernel_launch(void* const* d_in, const int* in_sizes, int n_in,
                              void* d_out, int out_size, void* d_ws, size_t ws_size,
                              hipStream_t stream) {
  const float* x = (const float*)d_in[0];
  const int* ei = (const int*)d_in[1];
  const int* batch = (const int*)d_in[2];
  const float* enc_w = (const float*)d_in[3];
  const float* enc_b = (const float*)d_in[4];
  const float* g_wl[2] = {(const float*)d_in[5], (const float*)d_in[11]};
  const float* g_bl[2] = {(const float*)d_in[6], (const float*)d_in[12]};
  const float* g_wr[2] = {(const float*)d_in[7], (const float*)d_in[13]};
  const float* g_br[2] = {(const float*)d_in[8], (const float*)d_in[14]};
  const float* g_att[2] = {(const float*)d_in[9], (const float*)d_in[15]};
  const float* g_bias[2] = {(const float*)d_in[10], (const float*)d_in[16]};
  const float* ln_g = (const float*)d_in[17];
  const float* ln_b = (const float*)d_in[18];
  const float* h1_w = (const float*)d_in[19];
  const float* h1_b = (const float*)d_in[20];
  const float* h2_w = (const float*)d_in[21];
  const float* h2_b = (const float*)d_in[22];
  float* out = (float*)d_out;

  const int N = in_sizes[2];          // 20000
  const int E = in_sizes[1] / 2;      // 320000
  const int DIN = in_sizes[0] / N;    // 128
  const int ET = E + N;
  const int H1 = in_sizes[20];        // 128
  const int OUT = in_sizes[22];       // 2
  const int G = out_size / OUT;       // 16

  char* base = (char*)d_ws;
  const size_t NH = (size_t)N * HIDDIM;
  __half* h16  = (__half*)base;                    // [N][256]
  __half* xl16 = h16 + NH;
  __half* xr16 = xl16 + NH;
  __half* x16  = xr16 + NH;                        // [N][DIN]
  __half* wtE  = x16 + (size_t)N * DIN;            // [256][DIN]
  __half* wt[4];
  wt[0] = wtE + (size_t)HIDDIM * DIN;
  wt[1] = wt[0] + (size_t)HIDDIM * HIDDIM;
  wt[2] = wt[1] + (size_t)HIDDIM * HIDDIM;
  wt[3] = wt[2] + (size_t)HIDDIM * HIDDIM;
  float* accf = (float*)(wt[3] + (size_t)HIDDIM * HIDDIM);   // [N][256] f32
  float* accd = accf + NH;                                   // [N][8] f32
  float* pooled = accd + (size_t)N * NHEADS;
  float* counts = pooled + (size_t)G * HIDDIM;
  int* deg    = (int*)(counts + G);
  int* rowptr = deg + N;
  int* cursor = rowptr + (N + 1);
  int* csr    = cursor + N;
  int* csrd   = csr + ET;

  const dim3 blk(256);
  const int eb = (ET + 255) / 256;
  const int nb = (N + 3) / 4;
  const dim3 mfma_grid(HIDDIM / 64, (N + 63) / 64);
  const int nwaves = (ET + WSLOTS - 1) / WSLOTS;
  const int segb = (nwaves + 3) / 4;

  // CSR build (graph identical for both layers)
  hipMemsetAsync(deg, 0, (size_t)N * sizeof(int), stream);
  hipMemsetAsync(cursor, 0, (size_t)N * sizeof(int), stream);
  hipMemsetAsync(pooled, 0, ((size_t)G * HIDDIM + G) * sizeof(float), stream);
  count_deg<<<eb, blk, 0, stream>>>(ei, deg, E, N);
  scan_deg<<<1, 1024, 0, stream>>>(deg, rowptr, N);
  fill_csr<<<eb, blk, 0, stream>>>(ei, rowptr, cursor, csr, csrd, E, N);

  // weight/input conversion
  cvt_f2h<<<(N * DIN + 255) / 256, blk, 0, stream>>>(x, x16, N * DIN);
  cvt_transpose<<<(DIN * HIDDIM + 255) / 256, blk, 0, stream>>>(enc_w, wtE, DIN, HIDDIM);
  cvt_transpose<<<(HIDDIM * HIDDIM + 255) / 256, blk, 0, stream>>>(g_wl[0], wt[0], HIDDIM, HIDDIM);
  cvt_transpose<<<(HIDDIM * HIDDIM + 255) / 256, blk, 0, stream>>>(g_wr[0], wt[1], HIDDIM, HIDDIM);
  cvt_transpose<<<(HIDDIM * HIDDIM + 255) / 256, blk, 0, stream>>>(g_wl[1], wt[2], HIDDIM, HIDDIM);
  cvt_transpose<<<(HIDDIM * HIDDIM + 255) / 256, blk, 0, stream>>>(g_wr[1], wt[3], HIDDIM, HIDDIM);

  // encoder: h16 = relu(x @ enc_w + enc_b)
  gemm_mfma<1><<<mfma_grid, blk, 0, stream>>>(
      (const _Float16*)x16, (const _Float16*)wtE, enc_b, (_Float16*)h16, N, HIDDIM, DIN);

  for (int L = 0; L < 2; ++L) {
    gemm_mfma<0><<<mfma_grid, blk, 0, stream>>>(
        (const _Float16*)h16, (const _Float16*)wt[2 * L + 0], g_bl[L], (_Float16*)xl16, N, HIDDIM, HIDDIM);
    gemm_mfma<0><<<mfma_grid, blk, 0, stream>>>(
        (const _Float16*)h16, (const _Float16*)wt[2 * L + 1], g_br[L], (_Float16*)xr16, N, HIDDIM, HIDDIM);
    zero_boundary<<<2 * nwaves, blk, 0, stream>>>(csrd, accf, accd, ET);
    edge_seg<<<segb, blk, 0, stream>>>(xl16, xr16, csr, csrd, rowptr, g_att[L], accf, accd, ET);
    if (L == 0) {
      node_fin<0><<<nb, blk, 0, stream>>>(accf, accd, g_bias[0], ln_g, ln_b,
                                          nullptr, nullptr, nullptr, h16, N);
    } else {
      node_fin<1><<<nb, blk, 0, stream>>>(accf, accd, g_bias[1], nullptr, nullptr,
                                          batch, pooled, counts, nullptr, N);
    }
  }
  head_kernel<<<1, blk, 0, stream>>>(pooled, counts, h1_w, h1_b, h2_w, h2_b, out, G, H1, OUT);
}